// Round 7
// baseline (488.913 us; speedup 1.0000x reference)
//
#include <hip/hip_runtime.h>
#include <hip/hip_bf16.h>
#include <cstdint>
#include <cstddef>

typedef __hip_bfloat16 bf16;
typedef __attribute__((ext_vector_type(8))) short short8;
typedef __attribute__((ext_vector_type(4))) short short4v;
typedef __attribute__((ext_vector_type(4))) float floatx4;

// Problem dims (all tensors float32; gates staged bf16 in LDS only)
#define BB 8
#define SS 4096
#define DIN 256
#define DH 512
#define CHUNK 16        // 8 chunks of 16 rows per 128-row m-tile

__device__ __forceinline__ float sh2f(short v) {
    unsigned int u = ((unsigned int)(unsigned short)v) << 16;
    float f; __builtin_memcpy(&f, &u, 4); return f;
}
__device__ __forceinline__ float frcp(float x) { return __builtin_amdgcn_rcpf(x); }
__device__ __forceinline__ short f2sh(float a) {
    bf16 bv = __float2bfloat16(a);
    short sv; __builtin_memcpy(&sv, &bv, 2); return sv;
}

// ---------------- kernel 0: fused prep -------------------------------------
// bx < tblk              : transpose W (f32 [256][512] x4 -> bf16 Wt[2048][256],
//                          gate-interleaved N: row = y*128 + g*32 + hh)
// tblk <= bx < tblk+cblk : convert x tile f32 -> bf16
// else                   : clear lookback flags + ticket counter (every pass)
__global__ __launch_bounds__(256) void prep(
    const float* __restrict__ Wi, const float* __restrict__ Wf,
    const float* __restrict__ Wo, const float* __restrict__ Wz,
    bf16* __restrict__ Wt,
    const float* __restrict__ X, bf16* __restrict__ Xb,
    unsigned int* __restrict__ Flag,
    int tblk, int cblk, int nwords)
{
    const int bx = blockIdx.x;
    const int tid = threadIdx.x;
    if (bx < tblk) {
        int o = bx * 256 + tid;               // 0..524287
        int r = o >> 8;                       // interleaved n index 0..2047
        int k = o & 255;
        int y = r >> 7;                       // h-group 0..15
        int c = r & 127;
        int g = c >> 5;                       // gate 0..3
        int h = y * 32 + (c & 31);            // 0..511
        const float* W = (g == 0) ? Wi : (g == 1) ? Wf : (g == 2) ? Wo : Wz;
        Wt[o] = __float2bfloat16(W[(size_t)k * DH + h]);
    } else if (bx < tblk + cblk) {
        const int idx = (bx - tblk) * 256 + tid;    // 4 f32 elements per thread
        float4 v = ((const float4*)X)[idx];
        bf16 o[4] = {__float2bfloat16(v.x), __float2bfloat16(v.y),
                     __float2bfloat16(v.z), __float2bfloat16(v.w)};
        ((short4v*)Xb)[idx] = *(const short4v*)o;
    } else {
        const int i = (bx - tblk - cblk) * 256 + tid;
        if (i < nwords) Flag[i] = 0u;
    }
}

// ---------------- kernel 1: GEMM + act + chained scan + emit (single pass) ---
__device__ __forceinline__ void load16_lds(const bf16* g, short* l)
{
    __builtin_amdgcn_global_load_lds(
        (const __attribute__((address_space(1))) unsigned int*)g,
        (__attribute__((address_space(3))) unsigned int*)l,
        16, 0, 0);
}

// TICKET-ORDERED decoupled lookback (rocPRIM pattern): logical tile id is an
// atomicAdd ticket, so logical order == execution-start order. A block spins
// only on a ticket acquired by an already-started block -> deadlock-free for
// ANY hardware dispatch order (the r6 blockIdx version assumed FIFO dispatch,
// which HIP does not guarantee -> hang).
// Ticket t: mt = t>>chShift (chain position 0..31), chain = t & (CH-1),
// chain = b*16 + y. mt-major => CH independent chains per generation.
__global__ __launch_bounds__(256) void gemm_scan(
    const bf16* __restrict__ Xb, const bf16* __restrict__ Wt,
    const float* __restrict__ bi, const float* __restrict__ bfv,
    const float* __restrict__ bo, const float* __restrict__ bz,
    float* __restrict__ Inc, unsigned int* __restrict__ Flag,
    unsigned int* __restrict__ Tick,
    float* __restrict__ out, int chShift)
{
    // K-loop: first 32 KB = 2 x 16 KB staging double-buffer (r2/r5-proven
    // drain schedule).  Epilogue: whole buffer = 128x132(pad) bf16 C-tile.
    __shared__ __align__(16) short smem[128 * 132];   // 33792 B
    __shared__ float cA[8][32], cBc[8][32], cBn[8][32];  // chunk affine maps
    __shared__ float sc[8][32], sn[8][32];               // chunk-start states
    __shared__ int s_ticket;

    const int tid  = threadIdx.x;
    if (tid == 0)
        s_ticket = (int)__hip_atomic_fetch_add(Tick, 1u, __ATOMIC_RELAXED,
                                               __HIP_MEMORY_SCOPE_AGENT);
    __syncthreads();
    const int t     = s_ticket;
    const int CH    = 1 << chShift;
    const int chain = t & (CH - 1);
    const int mt    = t >> chShift;       // 0..31
    const int b     = chain >> 4;
    const int y     = chain & 15;
    const int m0    = (b * 32 + mt) * 128;
    const int n0    = y * 128;

    const int wave = tid >> 6, lane = tid & 63;
    const int wm   = (wave >> 1) * 64, wn = (wave & 1) * 64;
    const int l15  = lane & 15;
    const int q    = lane >> 4;

    floatx4 acc[4][4];
#pragma unroll
    for (int i = 0; i < 4; i++)
#pragma unroll
        for (int j = 0; j < 4; j++) acc[i][j] = (floatx4){0.f, 0.f, 0.f, 0.f};

    const int r_ld = tid >> 2;
    const int c_ld = tid & 3;
    const bf16* agp0 = Xb + (size_t)(m0 + r_ld) * DIN + c_ld * 8;
    const bf16* agp1 = Xb + (size_t)(m0 + 64 + r_ld) * DIN + c_ld * 8;
    const bf16* bgp0 = Wt + (size_t)(n0 + r_ld) * DIN + c_ld * 8;
    const bf16* bgp1 = Wt + (size_t)(n0 + 64 + r_ld) * DIN + c_ld * 8;

#define STAGE(K0, BUF)                                            \
    do {                                                          \
        short* A_ = smem + (BUF) * 8192;                          \
        short* B_ = A_ + 4096;                                    \
        load16_lds(agp0 + (K0), &A_[tid * 8]);                    \
        load16_lds(agp1 + (K0), &A_[2048 + tid * 8]);             \
        load16_lds(bgp0 + (K0), &B_[tid * 8]);                    \
        load16_lds(bgp1 + (K0), &B_[2048 + tid * 8]);             \
    } while (0)

    STAGE(0, 0);
    asm volatile("s_waitcnt vmcnt(0)" ::: "memory");
    __builtin_amdgcn_s_barrier();

#pragma unroll
    for (int k = 0; k < 8; k++) {
        const int cur = k & 1;
        if (k < 7) STAGE((k + 1) * 32, cur ^ 1);
        const short* A = smem + cur * 8192;
        const short* B = A + 4096;
        short8 af[4], bfr[4];
#pragma unroll
        for (int ti = 0; ti < 4; ti++)
            af[ti] = *(const short8*)&A[(wm + ti * 16 + l15) * 32 + q * 8];
#pragma unroll
        for (int tj = 0; tj < 4; tj++)
            bfr[tj] = *(const short8*)&B[(wn + tj * 16 + l15) * 32 + q * 8];
#pragma unroll
        for (int ti = 0; ti < 4; ti++)
#pragma unroll
            for (int tj = 0; tj < 4; tj++)
                acc[ti][tj] = __builtin_amdgcn_mfma_f32_16x16x32_bf16(
                    af[ti], bfr[tj], acc[ti][tj], 0, 0, 0);
        // drain + compiler memory fence (rule #18: s_barrier alone is NoMem)
        asm volatile("s_waitcnt vmcnt(0) lgkmcnt(0)" ::: "memory");
        __builtin_amdgcn_s_barrier();
    }
#undef STAGE

    // -------- epilogue: bias + activation -> bf16 -> LDS C-tile [m][132] ----
#pragma unroll
    for (int ti = 0; ti < 4; ti++) {
        const int mrow = wm + ti * 16 + q * 4;       // tile-local row
#pragma unroll
        for (int tj = 0; tj < 4; tj++) {
            const int cb = wn + tj * 16;             // wave-uniform col base
            const int g  = cb >> 5;                  // gate 0..3 (uniform)
            const int c  = cb + l15;                 // tile-local col
            const float* bp = (g == 0) ? bi : (g == 1) ? bfv
                            : (g == 2) ? bo : bz;
            const float bsv = bp[y * 32 + (c & 31)];
#pragma unroll
            for (int r = 0; r < 4; r++) {
                const float v = acc[ti][tj][r] + bsv;
                float a;
                if (g == 0 || g == 1) {
                    a = __expf(fminf(fmaxf(v, -20.f), 0.f));     // exp(clip)
                } else if (g == 2) {
                    a = frcp(1.f + __expf(-v));                  // sigmoid
                } else {
                    a = 1.f - 2.f * frcp(__expf(2.f * v) + 1.f); // tanh
                }
                smem[(mrow + r) * 132 + c] = f2sh(a);
            }
        }
    }
    __syncthreads();

    const int hh = tid & 31;
    const int ch = tid >> 5;                         // chunk (16 rows) in tile
    const short* base = &smem[(ch * CHUNK) * 132];

    // -------- chunk carries: 8 chunks x 32 h, f32 affine composition --------
    {
        float A = 1.f, Bc = 0.f, Bn = 0.f;
#pragma unroll
        for (int s = 0; s < CHUNK; s++) {
            const short* rp = base + s * 132;
            const float iv = sh2f(rp[hh]);
            const float f  = sh2f(rp[32 + hh]);
            const float zv = sh2f(rp[96 + hh]);
            Bc = fmaf(f, Bc, iv * zv);
            Bn = fmaf(f, Bn, iv);
            A *= f;
        }
        cA[ch][hh] = A; cBc[ch][hh] = Bc; cBn[ch][hh] = Bn;
    }
    __syncthreads();

    // -------- decoupled lookback: wave 0 lanes 0..31 ------------------------
    if (tid < 32) {
        float c = 0.f, n = 1.f;
        if (mt > 0) {
            const int pt = t - CH;                   // predecessor ticket
            while (__hip_atomic_load(Flag + pt, __ATOMIC_ACQUIRE,
                                     __HIP_MEMORY_SCOPE_AGENT) == 0u)
                __builtin_amdgcn_s_sleep(2);
            c = __hip_atomic_load(Inc + (size_t)pt * 64 + hh,
                                  __ATOMIC_RELAXED, __HIP_MEMORY_SCOPE_AGENT);
            n = __hip_atomic_load(Inc + (size_t)pt * 64 + 32 + hh,
                                  __ATOMIC_RELAXED, __HIP_MEMORY_SCOPE_AGENT);
        }
#pragma unroll
        for (int k = 0; k < 8; k++) {
            sc[k][hh] = c; sn[k][hh] = n;
            const float a  = cA[k][hh];
            const float nc = fmaf(a, c, cBc[k][hh]);
            n = fmaf(a, n, cBn[k][hh]);
            c = nc;
        }
        __hip_atomic_store(Inc + (size_t)t * 64 + hh, c,
                           __ATOMIC_RELAXED, __HIP_MEMORY_SCOPE_AGENT);
        __hip_atomic_store(Inc + (size_t)t * 64 + 32 + hh, n,
                           __ATOMIC_RELAXED, __HIP_MEMORY_SCOPE_AGENT);
        // release orders the payload stores before the flag becomes visible
        __hip_atomic_store(Flag + t, 1u,
                           __ATOMIC_RELEASE, __HIP_MEMORY_SCOPE_AGENT);
    }
    __syncthreads();

    // -------- emit: replay chunk with true init, h -> out (f32) -------------
    {
        float c = sc[ch][hh];
        float n = sn[ch][hh];
        float* orow = out + (size_t)(m0 + ch * CHUNK) * DH + y * 32 + hh;
#pragma unroll
        for (int s = 0; s < CHUNK; s++) {
            const short* rp = base + s * 132;
            const float iv = sh2f(rp[hh]);
            const float f  = sh2f(rp[32 + hh]);
            const float ov = sh2f(rp[64 + hh]);
            const float zv = sh2f(rp[96 + hh]);
            c = fmaf(f, c, iv * zv);
            n = fmaf(f, n, iv);
            orow[(size_t)s * DH] = ov * c * frcp(n + 1e-6f);
        }
    }
}

// ---------------- launch -----------------------------------------------------
extern "C" void kernel_launch(void* const* d_in, const int* in_sizes, int n_in,
                              void* d_out, int out_size, void* d_ws, size_t ws_size,
                              hipStream_t stream)
{
    const float* x   = (const float*)d_in[0];
    const float* Wi  = (const float*)d_in[1];
    const float* bi  = (const float*)d_in[2];
    const float* Wf  = (const float*)d_in[3];
    const float* bfv = (const float*)d_in[4];
    const float* Wo  = (const float*)d_in[5];
    const float* bo  = (const float*)d_in[6];
    const float* Wz  = (const float*)d_in[7];
    const float* bz  = (const float*)d_in[8];
    float* out = (float*)d_out;

    // ws-adaptive: nb batches per pass (Wt + Xb + lookback scratch only)
    int nb = BB;
    while (nb > 1) {
        size_t need = (1u << 20)                         // Wt
                    + (size_t)nb * SS * DIN * 2          // Xb
                    + (size_t)nb * 512 * 64 * 4          // Inc
                    + ((size_t)nb * 512 + 1) * 4;        // Flag + ticket
        if (need <= ws_size) break;
        nb >>= 1;
    }

    bf16* Wt = (bf16*)d_ws;
    bf16* Xb = (bf16*)((char*)d_ws + (1u << 20));
    float* Inc = (float*)(Xb + (size_t)nb * SS * DIN);
    unsigned int* Flag = (unsigned int*)(Inc + (size_t)nb * 512 * 64);
    unsigned int* Tick = Flag + (size_t)nb * 512;

    int chShift = 4;                       // log2(nb*16)
    { int v = nb * 16; chShift = 31 - __builtin_clz(v); }

    for (int b0 = 0; b0 < BB; b0 += nb) {
        const float* Xsrc = x   + (size_t)b0 * SS * DIN;
        float*       Ob   = out + (size_t)b0 * SS * DH;
        const int tblk   = (b0 == 0) ? 2048 : 0;     // transpose only once
        const int cblk   = nb * 1024;
        const int nwords = nb * 512 + 1;             // flags + ticket counter
        const int fblk   = (nwords + 255) / 256;
        prep<<<tblk + cblk + fblk, 256, 0, stream>>>(
            Wi, Wf, Wo, Wz, Wt, Xsrc, Xb, Flag, tblk, cblk, nwords);
        gemm_scan<<<nb * 512, 256, 0, stream>>>(
            Xb, Wt, bi, bfv, bo, bz, Inc, Flag, Tick, Ob, chShift);
    }
}